// Round 11
// baseline (2067.053 us; speedup 1.0000x reference)
//
#include <hip/hip_runtime.h>

#define HIDN 128
#define VSTR 272           // V-buffer row stride in BYTES (17x16B -> conflict-free b128)
#define ASTR 132           // f32 activation row stride in floats (33x16B)

typedef __attribute__((ext_vector_type(8))) short short8;
typedef __attribute__((ext_vector_type(4))) float f32x4;

// ws layout (ushort units): [0,16384) W2b[128][128]; [16384,32768) W3b[128][128];
// [32768,34816) W4b[16][128] (rows 4..15 zero); [34816,35328) W1Tb[4][128]
#define WS_W2 0
#define WS_W3 16384
#define WS_W4 32768
#define WS_W1T 34816
#define WS_TOT 35328

// f32 -> bf16 round-to-nearest-even
__device__ __forceinline__ unsigned short f2bf(float f) {
    unsigned b = __float_as_uint(f);
    b += 0x7FFFu + ((b >> 16) & 1u);
    return (unsigned short)(b >> 16);
}

// ---------- prelude: one-time weight conversion to bf16 into ws ----------
__global__ void conv_w_kernel(const float* __restrict__ W1, const float* __restrict__ W2,
                              const float* __restrict__ W3, const float* __restrict__ W4,
                              unsigned short* __restrict__ wsb)
{
    const int idx = blockIdx.x * 256 + threadIdx.x;
    if (idx < 16384) {
        wsb[idx] = f2bf(W2[idx]);
    } else if (idx < 32768) {
        wsb[idx] = f2bf(W3[idx - 16384]);
    } else if (idx < 34816) {
        const int r = (idx - 32768) >> 7, j = (idx - 32768) & 127;
        wsb[idx] = (r < 4) ? f2bf(W4[r * HIDN + j]) : (unsigned short)0;
    } else if (idx < WS_TOT) {
        const int c = (idx - 34816) >> 7, j = (idx - 34816) & 127;
        wsb[idx] = f2bf(W1[j * 4 + c]);
    }
}

// One tangent layer, PING-PONG (src != dst; in-place interleaved RMW corrupts — R6/R8, 2-for-2).
// Wave owns V rows [wv*16, wv*16+16). A = W rows (bf16 from ws), B = V cols.
// D[m=unit ib*16+lk*4+r][n=sc=wv*16+lr] -> one b64 store per (ib). R7/R9-proven.
__device__ __forceinline__ void tangent_layer(const unsigned char* __restrict__ src,
                                              unsigned char* __restrict__ dst,
                                              const unsigned short* __restrict__ Wb,
                                              const unsigned char* __restrict__ msk, // [16][16] bytes
                                              int wv, int lr, int lk)
{
    short8 b[4];
    #pragma unroll
    for (int ks = 0; ks < 4; ++ks)
        b[ks] = *(const short8*)(src + (wv * 16 + lr) * VSTR + ks * 64 + lk * 16);

    const int sc = wv * 16 + lr;
    #pragma unroll
    for (int ib = 0; ib < 8; ++ib) {
        short8 a[4];
        #pragma unroll
        for (int ks = 0; ks < 4; ++ks)
            a[ks] = *(const short8*)(Wb + (ib * 16 + lr) * HIDN + ks * 32 + lk * 8);
        f32x4 c = (f32x4){0.f, 0.f, 0.f, 0.f};
        #pragma unroll
        for (int ks = 0; ks < 4; ++ks)
            c = __builtin_amdgcn_mfma_f32_16x16x32_bf16(a[ks], b[ks], c, 0, 0, 0);
        const unsigned bits = (msk[(sc >> 2) * 16 + ib * 2 + (lk >> 1)] >> ((lk & 1) * 4)) & 0xFu;
        unsigned long long pk = 0;
        #pragma unroll
        for (int r = 0; r < 4; ++r) {
            const unsigned short v = ((bits >> r) & 1u) ? f2bf(c[r]) : (unsigned short)0;
            pk |= (unsigned long long)v << (r * 16);
        }
        *(unsigned long long*)(dst + sc * VSTR + ib * 32 + lk * 8) = pk;
    }
}

__global__ __launch_bounds__(256, 3)
void wnn_jac_kernel(const float* __restrict__ u,
                    const float* __restrict__ W1, const float* __restrict__ b1,
                    const float* __restrict__ W2, const float* __restrict__ b2,
                    const float* __restrict__ W3, const float* __restrict__ b3,
                    const unsigned short* __restrict__ wsb,
                    float* __restrict__ out, int Btot)
{
    // [0,17408) vA ; [17408,34816) vB ; forward aliases [0,33792) as f32 abuf[64][132]
    __shared__ __align__(16) unsigned char smem[34816];
    __shared__ unsigned mlds32[3][64][4];   // [layer][sample][quarter] mask words (3072 B)
    __shared__ float jbuf[64 * 5];          // [sc][c'] stride 5 (1280 B)   -> total 39168 B

    unsigned char* vA = smem;
    unsigned char* vB = smem + 17408;
    float* abuf = (float*)smem;

    const int tid  = threadIdx.x;
    const long sg0 = (long)blockIdx.x * 64;

    // ================== FORWARD: lane = sample, wave = unit-quarter ==================
    {
        const int ls = tid & 63;                                        // sample
        const int wq = __builtin_amdgcn_readfirstlane(tid >> 6);        // uniform quarter
        const int i0 = wq * 32;
        const bool valid = (sg0 + ls < (long)Btot);

        float4 uv = make_float4(0.f, 0.f, 0.f, 0.f);
        if (valid) uv = *(const float4*)(u + (sg0 + ls) * 4);

        // ---- layer 1: 32 units/thread, bit-exact seq chain, bias after ----
        {
            unsigned m = 0;
            #pragma unroll
            for (int g4 = 0; g4 < 8; ++g4) {
                float4 hv;
                float* hp = &hv.x;
                #pragma unroll
                for (int e = 0; e < 4; ++e) {
                    const int i = i0 + g4 * 4 + e;
                    const float4 w = *(const float4*)(W1 + i * 4);
                    float h = 0.f;
                    h = fmaf(w.x, uv.x, h);
                    h = fmaf(w.y, uv.y, h);
                    h = fmaf(w.z, uv.z, h);
                    h = fmaf(w.w, uv.w, h);
                    h = h + b1[i];
                    if (h > 0.f) m |= (1u << (g4 * 4 + e));
                    hp[e] = fmaxf(h, 0.f);
                }
                *(float4*)(abuf + ls * ASTR + i0 + g4 * 4) = hv;
            }
            mlds32[0][ls][wq] = m;
        }
        __syncthreads();   // B1: a1 complete

        // ---- read full a1 row into registers (static indexing) ----
        float4 a4[32];
        #pragma unroll
        for (int t = 0; t < 32; ++t)
            a4[t] = *(const float4*)(abuf + ls * ASTR + t * 4);
        __syncthreads();   // B2: all reads done before in-place a2 writes

        // ---- layer 2: wave-uniform W rows (SGPR path), pure FMA chain ----
        {
            unsigned m = 0;
            #pragma unroll 2
            for (int i = 0; i < 32; ++i) {
                const float* wrow = W2 + (long)(i0 + i) * HIDN;
                float h = 0.f;
                #pragma unroll
                for (int t = 0; t < 32; ++t) {
                    h = fmaf(wrow[t * 4 + 0], a4[t].x, h);
                    h = fmaf(wrow[t * 4 + 1], a4[t].y, h);
                    h = fmaf(wrow[t * 4 + 2], a4[t].z, h);
                    h = fmaf(wrow[t * 4 + 3], a4[t].w, h);
                }
                h = h + b2[i0 + i];
                m |= (h > 0.f ? 1u : 0u) << i;
                abuf[ls * ASTR + i0 + i] = fmaxf(h, 0.f);
            }
            mlds32[1][ls][wq] = m;
        }
        __syncthreads();   // B3: a2 complete

        // ---- read full a2 row into registers ----
        #pragma unroll
        for (int t = 0; t < 32; ++t)
            a4[t] = *(const float4*)(abuf + ls * ASTR + t * 4);

        // ---- layer 3 (mask only, no LDS writes) ----
        {
            unsigned m = 0;
            #pragma unroll 2
            for (int i = 0; i < 32; ++i) {
                const float* wrow = W3 + (long)(i0 + i) * HIDN;
                float h = 0.f;
                #pragma unroll
                for (int t = 0; t < 32; ++t) {
                    h = fmaf(wrow[t * 4 + 0], a4[t].x, h);
                    h = fmaf(wrow[t * 4 + 1], a4[t].y, h);
                    h = fmaf(wrow[t * 4 + 2], a4[t].z, h);
                    h = fmaf(wrow[t * 4 + 3], a4[t].w, h);
                }
                h = h + b3[i0 + i];
                m |= (h > 0.f ? 1u : 0u) << i;
            }
            mlds32[2][ls][wq] = m;
        }
    }
    __syncthreads();   // B4: masks visible; abuf dead -> vA/vB reusable

    // ================== TANGENT: 4 subtiles of 16 samples (R9-proven machinery) ==================
    const unsigned char* ml8 = (const unsigned char*)mlds32;   // [3][64][16] bytes
    const int lane = tid & 63, wv = tid >> 6;
    const int lr = lane & 15, lk = lane >> 4;

    #pragma unroll 1
    for (int st = 0; st < 4; ++st) {
        __syncthreads();   // protects jbuf reuse across subtiles (and first-iter no-op)

        // ---- v1 build: vA row sc=ts*4+c = bf16(m1[sample][j] * W1[j][c]); rows wave-private ----
        {
            const int row = tid >> 2, kq = tid & 3;
            const int vs = row >> 2, vc = row & 3;
            const unsigned char* mrec = ml8 + (0 * 64 + st * 16 + vs) * 16;
            const unsigned short* w1t = wsb + WS_W1T + vc * HIDN;
            #pragma unroll
            for (int t = 0; t < 4; ++t) {
                const int j0 = kq * 32 + t * 8;
                const short8 w = *(const short8*)(w1t + j0);
                short8 fr;
                #pragma unroll
                for (int e = 0; e < 8; ++e) {
                    const int j = j0 + e;
                    fr[e] = ((mrec[j >> 3] >> (j & 7)) & 1u) ? w[e] : (short)0;
                }
                *(short8*)(vA + row * VSTR + j0 * 2) = fr;
            }
        }

        // ---- tangent layers 2,3 (ping-pong vA -> vB -> vA; wave-private rows, no barriers) ----
        tangent_layer(vA, vB, wsb + WS_W2, ml8 + (1 * 64 + st * 16) * 16, wv, lr, lk);
        tangent_layer(vB, vA, wsb + WS_W3, ml8 + (2 * 64 + st * 16) * 16, wv, lr, lk);

        // ---- Jf: D[c'][sc] = sum_j W4[c'][j] * V3[sc][j] ----
        {
            short8 a4f[4], b[4];
            #pragma unroll
            for (int ks = 0; ks < 4; ++ks) {
                a4f[ks] = *(const short8*)(wsb + WS_W4 + lr * HIDN + ks * 32 + lk * 8);
                b[ks]   = *(const short8*)(vA + (wv * 16 + lr) * VSTR + ks * 64 + lk * 16);
            }
            f32x4 c = (f32x4){0.f, 0.f, 0.f, 0.f};
            #pragma unroll
            for (int ks = 0; ks < 4; ++ks)
                c = __builtin_amdgcn_mfma_f32_16x16x32_bf16(a4f[ks], b[ks], c, 0, 0, 0);
            if (lk == 0) {
                const int sc = wv * 16 + lr;
                #pragma unroll
                for (int r = 0; r < 4; ++r)
                    jbuf[sc * 5 + r] = c[r];
            }
        }
        __syncthreads();   // jbuf complete

        // ---- epilogue: out[s][a][b'] = Jf[b'][a] - Jf[a][b'] ----
        if (tid < 64) {
            const int es = tid >> 2, ea = tid & 3;
            const long sg = sg0 + st * 16 + es;
            if (sg < (long)Btot) {
                float4 o;
                o.x = jbuf[(es * 4 + ea) * 5 + 0] - jbuf[(es * 4 + 0) * 5 + ea];
                o.y = jbuf[(es * 4 + ea) * 5 + 1] - jbuf[(es * 4 + 1) * 5 + ea];
                o.z = jbuf[(es * 4 + ea) * 5 + 2] - jbuf[(es * 4 + 2) * 5 + ea];
                o.w = jbuf[(es * 4 + ea) * 5 + 3] - jbuf[(es * 4 + 3) * 5 + ea];
                *(float4*)(out + sg * 16 + ea * 4) = o;
            }
        }
    }
}

extern "C" void kernel_launch(void* const* d_in, const int* in_sizes, int n_in,
                              void* d_out, int out_size, void* d_ws, size_t ws_size,
                              hipStream_t stream)
{
    const float* u  = (const float*)d_in[0];
    const float* W1 = (const float*)d_in[1];
    const float* b1 = (const float*)d_in[2];
    const float* W2 = (const float*)d_in[3];
    const float* b2 = (const float*)d_in[4];
    const float* W3 = (const float*)d_in[5];
    const float* b3 = (const float*)d_in[6];
    const float* W4 = (const float*)d_in[7];
    // d_in[8] = b4: unused (bias does not enter the Jacobian)
    float* out = (float*)d_out;
    unsigned short* wsb = (unsigned short*)d_ws;   // needs 70656 B

    const int B = in_sizes[0] / 4;
    hipLaunchKernelGGL(conv_w_kernel, dim3((WS_TOT + 255) / 256), dim3(256), 0, stream,
                       W1, W2, W3, W4, wsb);
    const int nblocks = (B + 63) / 64;
    hipLaunchKernelGGL(wnn_jac_kernel, dim3(nblocks), dim3(256), 0, stream,
                       u, W1, b1, W2, b2, W3, b3, wsb, out, B);
}

// Round 12
// 725.471 us; speedup vs baseline: 2.8493x; 2.8493x over previous
//
#include <hip/hip_runtime.h>

#define HIDN 128
#define SAMP 16            // samples per block
#define VSTR 272           // V-buffer row stride in BYTES (17x16B -> conflict-free b128)
#define ASTR 132           // f32 activation row stride (floats)

typedef __attribute__((ext_vector_type(8))) short short8;
typedef __attribute__((ext_vector_type(4))) float f32x4;

// ws layout (ushort units): [0,16384) W2b[128][128]; [16384,32768) W3b[128][128];
// [32768,34816) W4b[16][128] (rows 4..15 zero); [34816,35328) W1Tb[4][128]
#define WS_W2 0
#define WS_W3 16384
#define WS_W4 32768
#define WS_W1T 34816
#define WS_TOT 35328

// f32 -> bf16 round-to-nearest-even
__device__ __forceinline__ unsigned short f2bf(float f) {
    unsigned b = __float_as_uint(f);
    b += 0x7FFFu + ((b >> 16) & 1u);
    return (unsigned short)(b >> 16);
}

// ---------- prelude: one-time weight conversion to bf16 into ws ----------
__global__ void conv_w_kernel(const float* __restrict__ W1, const float* __restrict__ W2,
                              const float* __restrict__ W3, const float* __restrict__ W4,
                              unsigned short* __restrict__ wsb)
{
    const int idx = blockIdx.x * 256 + threadIdx.x;
    if (idx < 16384) {
        wsb[idx] = f2bf(W2[idx]);
    } else if (idx < 32768) {
        wsb[idx] = f2bf(W3[idx - 16384]);
    } else if (idx < 34816) {
        const int r = (idx - 32768) >> 7, j = (idx - 32768) & 127;
        wsb[idx] = (r < 4) ? f2bf(W4[r * HIDN + j]) : (unsigned short)0;
    } else if (idx < WS_TOT) {
        const int c = (idx - 34816) >> 7, j = (idx - 34816) & 127;
        wsb[idx] = f2bf(W1[j * 4 + c]);
    }
}

// One tangent layer, PING-PONG (src != dst; in-place corrupts — R6/R8, 2-for-2).
// Wave owns V rows [wv*16, wv*16+16). A = W rows (bf16 from ws), B = V cols.
// D[m=unit ib*16+lk*4+r][n=sc=wv*16+lr] -> one b64 store per (ib). R7/R9-proven.
__device__ __forceinline__ void tangent_layer(const unsigned char* __restrict__ src,
                                              unsigned char* __restrict__ dst,
                                              const unsigned short* __restrict__ Wb,
                                              const unsigned char* __restrict__ msk, // [16][16]
                                              int wv, int lr, int lk)
{
    short8 b[4];
    #pragma unroll
    for (int ks = 0; ks < 4; ++ks)
        b[ks] = *(const short8*)(src + (wv * 16 + lr) * VSTR + ks * 64 + lk * 16);

    const int sc = wv * 16 + lr;
    #pragma unroll
    for (int ib = 0; ib < 8; ++ib) {
        short8 a[4];
        #pragma unroll
        for (int ks = 0; ks < 4; ++ks)
            a[ks] = *(const short8*)(Wb + (ib * 16 + lr) * HIDN + ks * 32 + lk * 8);
        f32x4 c = (f32x4){0.f, 0.f, 0.f, 0.f};
        #pragma unroll
        for (int ks = 0; ks < 4; ++ks)
            c = __builtin_amdgcn_mfma_f32_16x16x32_bf16(a[ks], b[ks], c, 0, 0, 0);
        const unsigned bits = (msk[(sc >> 2) * 16 + ib * 2 + (lk >> 1)] >> ((lk & 1) * 4)) & 0xFu;
        unsigned long long pk = 0;
        #pragma unroll
        for (int r = 0; r < 4; ++r) {
            const unsigned short v = ((bits >> r) & 1u) ? f2bf(c[r]) : (unsigned short)0;
            pk |= (unsigned long long)v << (r * 16);
        }
        *(unsigned long long*)(dst + sc * VSTR + ib * 32 + lk * 8) = pk;
    }
}

__global__ __launch_bounds__(256, 3)
void wnn_jac_kernel(const float* __restrict__ u,
                    const float* __restrict__ W1, const float* __restrict__ b1,
                    const float* __restrict__ W2, const float* __restrict__ b2,
                    const float* __restrict__ W3, const float* __restrict__ b3,
                    const unsigned short* __restrict__ wsb,
                    float* __restrict__ out, int Btot)
{
    __shared__ __align__(16) unsigned char vA[64 * VSTR];   // 17408 B
    __shared__ __align__(16) unsigned char vB[64 * VSTR];   // 17408 B
    __shared__ unsigned char mlds[3][SAMP][16];             // 768 B
    __shared__ float jbuf[64 * 5];                          // 1280 B

    float* abufA = (float*)vA;      // forward a1: f32 [16][132] (aliased, sync-separated)
    float* abufB = (float*)vB;      // forward a2

    const int tid  = threadIdx.x;
    const int s    = tid & 15;      // sample (forward phase)
    const int gg   = tid >> 4;      // unit group 0..15 (8 units each)
    const int i0   = gg * 8;
    const long sg0 = (long)blockIdx.x * SAMP;
    const bool valid = (sg0 + s < (long)Btot);

    float4 uv = make_float4(0.f, 0.f, 0.f, 0.f);
    if (valid) uv = *(const float4*)(u + (sg0 + s) * 4);

    // ======== forward layer 1 (bit-exact: seq f32 fma chain from 0, bias after) ========
    {
        unsigned m = 0;
        #pragma unroll
        for (int ii = 0; ii < 8; ++ii) {
            const int i = i0 + ii;
            const float4 w = *(const float4*)(W1 + i * 4);
            float h = 0.f;
            h = fmaf(w.x, uv.x, h);
            h = fmaf(w.y, uv.y, h);
            h = fmaf(w.z, uv.z, h);
            h = fmaf(w.w, uv.w, h);
            h = h + b1[i];
            if (h > 0.f) m |= (1u << ii);
            abufA[s * ASTR + i] = fmaxf(h, 0.f);
        }
        mlds[0][s][gg] = (unsigned char)m;
    }
    __syncthreads();   // B1

    // ======== forward layer 2 — explicit 3-slot rotating prefetch (R12 change) ========
    // Loads of k-tile jc+2 are issued BEFORE the FMAs of tile jc, into distinct
    // named buffers (all indices compile-time after full unroll). The FMA chain
    // per unit stays strictly jc-ascending, x,y,z,w -> bit-exact masks.
    {
        float acc[8];
        #pragma unroll
        for (int ii = 0; ii < 8; ++ii) acc[ii] = 0.f;
        const float* arow  = abufA + s * ASTR;
        const float* wbase = W2 + (long)i0 * HIDN;

        float4 wb[3][8];
        float4 ab[3];
        #pragma unroll
        for (int p = 0; p < 2; ++p) {
            ab[p] = *(const float4*)(arow + p * 4);
            #pragma unroll
            for (int ii = 0; ii < 8; ++ii)
                wb[p][ii] = *(const float4*)(wbase + ii * HIDN + p * 4);
        }
        #pragma unroll
        for (int jc = 0; jc < 32; ++jc) {
            const int cur = jc % 3;
            if (jc + 2 < 32) {
                const int nxt = (jc + 2) % 3;
                ab[nxt] = *(const float4*)(arow + (jc + 2) * 4);
                #pragma unroll
                for (int ii = 0; ii < 8; ++ii)
                    wb[nxt][ii] = *(const float4*)(wbase + ii * HIDN + (jc + 2) * 4);
            }
            const float4 av = ab[cur];
            #pragma unroll
            for (int ii = 0; ii < 8; ++ii) {
                const float4 w = wb[cur][ii];
                float a = acc[ii];
                a = fmaf(w.x, av.x, a);
                a = fmaf(w.y, av.y, a);
                a = fmaf(w.z, av.z, a);
                a = fmaf(w.w, av.w, a);
                acc[ii] = a;
            }
        }
        unsigned m = 0;
        #pragma unroll
        for (int ii = 0; ii < 8; ++ii) {
            const float h = acc[ii] + b2[i0 + ii];
            if (h > 0.f) m |= (1u << ii);
            abufB[s * ASTR + i0 + ii] = fmaxf(h, 0.f);   // other buffer: no WAR on abufA
        }
        mlds[1][s][gg] = (unsigned char)m;
    }
    __syncthreads();   // B2

    // ======== forward layer 3 (mask only) — same pipelined pattern ========
    {
        float acc[8];
        #pragma unroll
        for (int ii = 0; ii < 8; ++ii) acc[ii] = 0.f;
        const float* arow  = abufB + s * ASTR;
        const float* wbase = W3 + (long)i0 * HIDN;

        float4 wb[3][8];
        float4 ab[3];
        #pragma unroll
        for (int p = 0; p < 2; ++p) {
            ab[p] = *(const float4*)(arow + p * 4);
            #pragma unroll
            for (int ii = 0; ii < 8; ++ii)
                wb[p][ii] = *(const float4*)(wbase + ii * HIDN + p * 4);
        }
        #pragma unroll
        for (int jc = 0; jc < 32; ++jc) {
            const int cur = jc % 3;
            if (jc + 2 < 32) {
                const int nxt = (jc + 2) % 3;
                ab[nxt] = *(const float4*)(arow + (jc + 2) * 4);
                #pragma unroll
                for (int ii = 0; ii < 8; ++ii)
                    wb[nxt][ii] = *(const float4*)(wbase + ii * HIDN + (jc + 2) * 4);
            }
            const float4 av = ab[cur];
            #pragma unroll
            for (int ii = 0; ii < 8; ++ii) {
                const float4 w = wb[cur][ii];
                float a = acc[ii];
                a = fmaf(w.x, av.x, a);
                a = fmaf(w.y, av.y, a);
                a = fmaf(w.z, av.z, a);
                a = fmaf(w.w, av.w, a);
                acc[ii] = a;
            }
        }
        unsigned m = 0;
        #pragma unroll
        for (int ii = 0; ii < 8; ++ii) {
            const float h = acc[ii] + b3[i0 + ii];
            if (h > 0.f) m |= (1u << ii);
        }
        mlds[2][s][gg] = (unsigned char)m;
    }
    __syncthreads();   // B3 — last barrier before epilogue (tangent chain is wave-private)

    // ======== v1 build: vA row sc=s*4+c = bf16(m1[s][j] * W1[j][c]) ========
    {
        const int row = tid >> 2, kq = tid & 3;   // wave wv writes rows [wv*16, wv*16+16)
        const int vs = row >> 2, vc = row & 3;
        const unsigned short* w1t = wsb + WS_W1T + vc * HIDN;
        #pragma unroll
        for (int t = 0; t < 4; ++t) {
            const int j0 = kq * 32 + t * 8;
            const short8 w = *(const short8*)(w1t + j0);
            short8 fr;
            #pragma unroll
            for (int e = 0; e < 8; ++e) {
                const int j = j0 + e;
                fr[e] = ((mlds[0][vs][j >> 3] >> (j & 7)) & 1u) ? w[e] : (short)0;
            }
            *(short8*)(vA + row * VSTR + j0 * 2) = fr;
        }
    }

    const int lane = tid & 63, wv = tid >> 6;
    const int lr = lane & 15, lk = lane >> 4;

    // ======== tangent layers 2,3 (ping-pong vA -> vB -> vA; no barriers: wave-private rows) ========
    tangent_layer(vA, vB, wsb + WS_W2, &mlds[1][0][0], wv, lr, lk);
    tangent_layer(vB, vA, wsb + WS_W3, &mlds[2][0][0], wv, lr, lk);

    // ======== Jf: D[c'][sc] = sum_j W4[c'][j] * V3[sc][j] (W4b rows 4..15 zero) ========
    {
        short8 a4[4], b[4];
        #pragma unroll
        for (int ks = 0; ks < 4; ++ks) {
            a4[ks] = *(const short8*)(wsb + WS_W4 + lr * HIDN + ks * 32 + lk * 8);
            b[ks]  = *(const short8*)(vA + (wv * 16 + lr) * VSTR + ks * 64 + lk * 16);
        }
        f32x4 c = (f32x4){0.f, 0.f, 0.f, 0.f};
        #pragma unroll
        for (int ks = 0; ks < 4; ++ks)
            c = __builtin_amdgcn_mfma_f32_16x16x32_bf16(a4[ks], b[ks], c, 0, 0, 0);
        if (lk == 0) {   // c' = lk*4+r = r (0..3); sc = wv*16+lr
            const int sc = wv * 16 + lr;
            #pragma unroll
            for (int r = 0; r < 4; ++r)
                jbuf[sc * 5 + r] = c[r];
        }
    }
    __syncthreads();   // B4 — jbuf cross-wave before epilogue

    // ======== epilogue: out[s][a][b'] = Jf[b'][a] - Jf[a][b']; Jf[c'][c] = jbuf[(s*4+c)*5+c'] ========
    if (tid < 64) {
        const int es = tid >> 2, ea = tid & 3;
        if (sg0 + es < (long)Btot) {
            float4 o;
            o.x = jbuf[(es * 4 + ea) * 5 + 0] - jbuf[(es * 4 + 0) * 5 + ea];
            o.y = jbuf[(es * 4 + ea) * 5 + 1] - jbuf[(es * 4 + 1) * 5 + ea];
            o.z = jbuf[(es * 4 + ea) * 5 + 2] - jbuf[(es * 4 + 2) * 5 + ea];
            o.w = jbuf[(es * 4 + ea) * 5 + 3] - jbuf[(es * 4 + 3) * 5 + ea];
            *(float4*)(out + (sg0 + es) * 16 + ea * 4) = o;
        }
    }
}

extern "C" void kernel_launch(void* const* d_in, const int* in_sizes, int n_in,
                              void* d_out, int out_size, void* d_ws, size_t ws_size,
                              hipStream_t stream)
{
    const float* u  = (const float*)d_in[0];
    const float* W1 = (const float*)d_in[1];
    const float* b1 = (const float*)d_in[2];
    const float* W2 = (const float*)d_in[3];
    const float* b2 = (const float*)d_in[4];
    const float* W3 = (const float*)d_in[5];
    const float* b3 = (const float*)d_in[6];
    const float* W4 = (const float*)d_in[7];
    // d_in[8] = b4: unused (bias does not enter the Jacobian)
    float* out = (float*)d_out;
    unsigned short* wsb = (unsigned short*)d_ws;   // needs 70656 B

    const int B = in_sizes[0] / 4;
    hipLaunchKernelGGL(conv_w_kernel, dim3((WS_TOT + 255) / 256), dim3(256), 0, stream,
                       W1, W2, W3, W4, wsb);
    const int nblocks = (B + SAMP - 1) / SAMP;
    hipLaunchKernelGGL(wnn_jac_kernel, dim3(nblocks), dim3(256), 0, stream,
                       u, W1, b1, W2, b2, W3, b3, wsb, out, B);
}

// Round 13
// 705.656 us; speedup vs baseline: 2.9293x; 1.0281x over previous
//
#include <hip/hip_runtime.h>

#define HIDN 128
#define VSTR 272           // V-buffer row stride in BYTES (17x16B -> conflict-free b128)
#define ASTR 132           // f32 activation row stride (floats)

typedef __attribute__((ext_vector_type(8))) short short8;
typedef __attribute__((ext_vector_type(4))) float f32x4;

// ws layout (ushort units): [0,16384) W2b[128][128]; [16384,32768) W3b[128][128];
// [32768,34816) W4b[16][128] (rows 4..15 zero); [34816,35328) W1Tb[4][128]
#define WS_W2 0
#define WS_W3 16384
#define WS_W4 32768
#define WS_W1T 34816
#define WS_TOT 35328

// Batched 8-row W load (f32x4 each), rows 512B apart. Loads + waitcnt live in
// ONE asm block: 8 loads go into flight together (concurrency 8 vs the
// compiler's load->wait->use concurrency 1), and consumers depend on the
// outputs, so nothing can be hoisted above the wait.
#define LOAD_W8(dst, base)                                                    \
    asm volatile("global_load_dwordx4 %0, %8, off\n\t"                        \
                 "global_load_dwordx4 %1, %8, off offset:512\n\t"             \
                 "global_load_dwordx4 %2, %8, off offset:1024\n\t"            \
                 "global_load_dwordx4 %3, %8, off offset:1536\n\t"            \
                 "global_load_dwordx4 %4, %8, off offset:2048\n\t"            \
                 "global_load_dwordx4 %5, %8, off offset:2560\n\t"            \
                 "global_load_dwordx4 %6, %8, off offset:3072\n\t"            \
                 "global_load_dwordx4 %7, %8, off offset:3584\n\t"            \
                 "s_waitcnt vmcnt(0)"                                         \
                 : "=&v"(dst[0]), "=&v"(dst[1]), "=&v"(dst[2]), "=&v"(dst[3]),\
                   "=&v"(dst[4]), "=&v"(dst[5]), "=&v"(dst[6]), "=&v"(dst[7]) \
                 : "v"(base)                                                  \
                 : "memory")

// Batched 4-slice bf16 W load (short8 each), slices 64B apart.
#define LOAD_A4(dst, base)                                                    \
    asm volatile("global_load_dwordx4 %0, %4, off\n\t"                        \
                 "global_load_dwordx4 %1, %4, off offset:64\n\t"              \
                 "global_load_dwordx4 %2, %4, off offset:128\n\t"             \
                 "global_load_dwordx4 %3, %4, off offset:192\n\t"             \
                 "s_waitcnt vmcnt(0)"                                         \
                 : "=&v"(dst[0]), "=&v"(dst[1]), "=&v"(dst[2]), "=&v"(dst[3]) \
                 : "v"(base)                                                  \
                 : "memory")

// f32 -> bf16 round-to-nearest-even
__device__ __forceinline__ unsigned short f2bf(float f) {
    unsigned b = __float_as_uint(f);
    b += 0x7FFFu + ((b >> 16) & 1u);
    return (unsigned short)(b >> 16);
}

// ---------- prelude: one-time weight conversion to bf16 into ws ----------
__global__ void conv_w_kernel(const float* __restrict__ W1, const float* __restrict__ W2,
                              const float* __restrict__ W3, const float* __restrict__ W4,
                              unsigned short* __restrict__ wsb)
{
    const int idx = blockIdx.x * 256 + threadIdx.x;
    if (idx < 16384) {
        wsb[idx] = f2bf(W2[idx]);
    } else if (idx < 32768) {
        wsb[idx] = f2bf(W3[idx - 16384]);
    } else if (idx < 34816) {
        const int r = (idx - 32768) >> 7, j = (idx - 32768) & 127;
        wsb[idx] = (r < 4) ? f2bf(W4[r * HIDN + j]) : (unsigned short)0;
    } else if (idx < WS_TOT) {
        const int c = (idx - 34816) >> 7, j = (idx - 34816) & 127;
        wsb[idx] = f2bf(W1[j * 4 + c]);
    }
}

// One tangent layer, PING-PONG (src != dst; in-place corrupts — R6/R8, 2-for-2).
// Wave owns V rows [wv*16, wv*16+16). A = W rows (bf16 from ws), B = V cols.
// D[m=unit ib*16+lk*4+r][n=sc=wv*16+lr] -> one b64 store per (ib). R7/R9/R11-proven.
__device__ __forceinline__ void tangent_layer(const unsigned char* __restrict__ src,
                                              unsigned char* __restrict__ dst,
                                              const unsigned short* __restrict__ Wb,
                                              const unsigned char* __restrict__ msk, // [16][16]
                                              int wv, int lr, int lk)
{
    short8 b[4];
    #pragma unroll
    for (int ks = 0; ks < 4; ++ks)
        b[ks] = *(const short8*)(src + (wv * 16 + lr) * VSTR + ks * 64 + lk * 16);

    const int sc = wv * 16 + lr;
    #pragma unroll
    for (int ib = 0; ib < 8; ++ib) {
        short8 a[4];
        LOAD_A4(a, Wb + (ib * 16 + lr) * HIDN + lk * 8);
        f32x4 c = (f32x4){0.f, 0.f, 0.f, 0.f};
        #pragma unroll
        for (int ks = 0; ks < 4; ++ks)
            c = __builtin_amdgcn_mfma_f32_16x16x32_bf16(a[ks], b[ks], c, 0, 0, 0);
        const unsigned bits = (msk[(sc >> 2) * 16 + ib * 2 + (lk >> 1)] >> ((lk & 1) * 4)) & 0xFu;
        unsigned long long pk = 0;
        #pragma unroll
        for (int r = 0; r < 4; ++r) {
            const unsigned short v = ((bits >> r) & 1u) ? f2bf(c[r]) : (unsigned short)0;
            pk |= (unsigned long long)v << (r * 16);
        }
        *(unsigned long long*)(dst + sc * VSTR + ib * 32 + lk * 8) = pk;
    }
}

__global__ __launch_bounds__(256, 4)
void wnn_jac_kernel(const float* __restrict__ u,
                    const float* __restrict__ W1, const float* __restrict__ b1,
                    const float* __restrict__ W2, const float* __restrict__ b2,
                    const float* __restrict__ W3, const float* __restrict__ b3,
                    const unsigned short* __restrict__ wsb,
                    float* __restrict__ out, int Btot)
{
    // [0,17408) vA ; [17408,34816) vB ; forward aliases [0,33792) as f32 abuf[64][132]
    __shared__ __align__(16) unsigned char smem[34816];
    __shared__ unsigned char mlds8[3][64][16];   // [layer][sample][unit>>3] (3072 B)
    __shared__ float jbuf[64 * 5];               // [sc][c'] stride 5 (1280 B)

    unsigned char* vA = smem;
    unsigned char* vB = smem + 17408;
    float* abuf = (float*)smem;

    const int tid  = threadIdx.x;
    const int sgp  = tid >> 4;        // sample group: samples sgp*4 .. +4
    const int ugp  = tid & 15;        // unit group: units ugp*8 .. +8
    const int i0   = ugp * 8;
    const long sg0 = (long)blockIdx.x * 64;

    // ======== forward layer 1: 4 samples x 8 units (bit-exact seq chain, bias after) ========
    {
        float4 uvv[4];
        #pragma unroll
        for (int sm = 0; sm < 4; ++sm) {
            const long sg = sg0 + sgp * 4 + sm;
            uvv[sm] = (sg < (long)Btot) ? *(const float4*)(u + sg * 4)
                                        : make_float4(0.f, 0.f, 0.f, 0.f);
        }
        float4 w1r[8];
        #pragma unroll
        for (int ii = 0; ii < 8; ++ii)
            w1r[ii] = *(const float4*)(W1 + (i0 + ii) * 4);
        #pragma unroll
        for (int sm = 0; sm < 4; ++sm) {
            const int s = sgp * 4 + sm;
            unsigned m = 0;
            #pragma unroll
            for (int ii = 0; ii < 8; ++ii) {
                float h = 0.f;
                h = fmaf(w1r[ii].x, uvv[sm].x, h);
                h = fmaf(w1r[ii].y, uvv[sm].y, h);
                h = fmaf(w1r[ii].z, uvv[sm].z, h);
                h = fmaf(w1r[ii].w, uvv[sm].w, h);
                h = h + b1[i0 + ii];
                if (h > 0.f) m |= (1u << ii);
                abuf[s * ASTR + i0 + ii] = fmaxf(h, 0.f);
            }
            mlds8[0][s][ugp] = (unsigned char)m;
        }
    }
    __syncthreads();   // B1: a1 complete

    // ======== forward layer 2: 4x8 register tile, asm-batched W loads ========
    float acc[4][8];
    {
        #pragma unroll
        for (int sm = 0; sm < 4; ++sm)
            #pragma unroll
            for (int ii = 0; ii < 8; ++ii) acc[sm][ii] = 0.f;

        #pragma unroll 1
        for (int jc = 0; jc < 32; ++jc) {
            f32x4 av[4];
            #pragma unroll
            for (int sm = 0; sm < 4; ++sm)
                av[sm] = *(const f32x4*)(abuf + (sgp * 4 + sm) * ASTR + jc * 4);
            f32x4 wreg[8];
            LOAD_W8(wreg, W2 + (long)i0 * HIDN + jc * 4);
            #pragma unroll
            for (int sm = 0; sm < 4; ++sm) {
                #pragma unroll
                for (int ii = 0; ii < 8; ++ii) {
                    float a = acc[sm][ii];
                    a = fmaf(wreg[ii][0], av[sm][0], a);
                    a = fmaf(wreg[ii][1], av[sm][1], a);
                    a = fmaf(wreg[ii][2], av[sm][2], a);
                    a = fmaf(wreg[ii][3], av[sm][3], a);
                    acc[sm][ii] = a;
                }
            }
        }
    }
    __syncthreads();   // B2: all a1 reads done -> safe to overwrite abuf with a2

    {
        #pragma unroll
        for (int sm = 0; sm < 4; ++sm) {
            const int s = sgp * 4 + sm;
            unsigned m = 0;
            #pragma unroll
            for (int ii = 0; ii < 8; ++ii) {
                const float h = acc[sm][ii] + b2[i0 + ii];
                if (h > 0.f) m |= (1u << ii);
                abuf[s * ASTR + i0 + ii] = fmaxf(h, 0.f);
            }
            mlds8[1][s][ugp] = (unsigned char)m;
        }
    }
    __syncthreads();   // B3: a2 complete

    // ======== forward layer 3 (mask only) ========
    {
        #pragma unroll
        for (int sm = 0; sm < 4; ++sm)
            #pragma unroll
            for (int ii = 0; ii < 8; ++ii) acc[sm][ii] = 0.f;

        #pragma unroll 1
        for (int jc = 0; jc < 32; ++jc) {
            f32x4 av[4];
            #pragma unroll
            for (int sm = 0; sm < 4; ++sm)
                av[sm] = *(const f32x4*)(abuf + (sgp * 4 + sm) * ASTR + jc * 4);
            f32x4 wreg[8];
            LOAD_W8(wreg, W3 + (long)i0 * HIDN + jc * 4);
            #pragma unroll
            for (int sm = 0; sm < 4; ++sm) {
                #pragma unroll
                for (int ii = 0; ii < 8; ++ii) {
                    float a = acc[sm][ii];
                    a = fmaf(wreg[ii][0], av[sm][0], a);
                    a = fmaf(wreg[ii][1], av[sm][1], a);
                    a = fmaf(wreg[ii][2], av[sm][2], a);
                    a = fmaf(wreg[ii][3], av[sm][3], a);
                    acc[sm][ii] = a;
                }
            }
        }
        #pragma unroll
        for (int sm = 0; sm < 4; ++sm) {
            const int s = sgp * 4 + sm;
            unsigned m = 0;
            #pragma unroll
            for (int ii = 0; ii < 8; ++ii) {
                const float h = acc[sm][ii] + b3[i0 + ii];
                if (h > 0.f) m |= (1u << ii);
            }
            mlds8[2][s][ugp] = (unsigned char)m;
        }
    }

    // ================== TANGENT: 4 subtiles of 16 samples (R11-validated) ==================
    const unsigned char* ml8 = &mlds8[0][0][0];
    const int lane = tid & 63, wv = tid >> 6;
    const int lr = lane & 15, lk = lane >> 4;

    #pragma unroll 1
    for (int st = 0; st < 4; ++st) {
        __syncthreads();   // 1st iter: masks visible + abuf dead; later: jbuf/vA reuse safe

        // ---- v1 build: vA row sc=s_local*4+c = bf16(m1[sample][j] * W1[j][c]) ----
        {
            const int row = tid >> 2, kq = tid & 3;
            const int vs = row >> 2, vc = row & 3;
            const unsigned char* mrec = ml8 + (0 * 64 + st * 16 + vs) * 16;
            const unsigned short* w1t = wsb + WS_W1T + vc * HIDN;
            #pragma unroll
            for (int t = 0; t < 4; ++t) {
                const int j0 = kq * 32 + t * 8;
                const short8 w = *(const short8*)(w1t + j0);
                short8 fr;
                #pragma unroll
                for (int e = 0; e < 8; ++e) {
                    const int j = j0 + e;
                    fr[e] = ((mrec[j >> 3] >> (j & 7)) & 1u) ? w[e] : (short)0;
                }
                *(short8*)(vA + row * VSTR + j0 * 2) = fr;
            }
        }

        // ---- tangent layers 2,3 (ping-pong vA -> vB -> vA; wave-private rows) ----
        tangent_layer(vA, vB, wsb + WS_W2, ml8 + (1 * 64 + st * 16) * 16, wv, lr, lk);
        tangent_layer(vB, vA, wsb + WS_W3, ml8 + (2 * 64 + st * 16) * 16, wv, lr, lk);

        // ---- Jf: D[c'][sc] = sum_j W4[c'][j] * V3[sc][j] ----
        {
            short8 a4f[4], b[4];
            #pragma unroll
            for (int ks = 0; ks < 4; ++ks) {
                a4f[ks] = *(const short8*)(wsb + WS_W4 + lr * HIDN + ks * 32 + lk * 8);
                b[ks]   = *(const short8*)(vA + (wv * 16 + lr) * VSTR + ks * 64 + lk * 16);
            }
            f32x4 c = (f32x4){0.f, 0.f, 0.f, 0.f};
            #pragma unroll
            for (int ks = 0; ks < 4; ++ks)
                c = __builtin_amdgcn_mfma_f32_16x16x32_bf16(a4f[ks], b[ks], c, 0, 0, 0);
            if (lk == 0) {
                const int sc = wv * 16 + lr;
                #pragma unroll
                for (int r = 0; r < 4; ++r)
                    jbuf[sc * 5 + r] = c[r];
            }
        }
        __syncthreads();   // jbuf complete

        // ---- epilogue: out[s][a][b'] = Jf[b'][a] - Jf[a][b'] ----
        if (tid < 64) {
            const int es = tid >> 2, ea = tid & 3;
            const long sg = sg0 + st * 16 + es;
            if (sg < (long)Btot) {
                float4 o;
                o.x = jbuf[(es * 4 + ea) * 5 + 0] - jbuf[(es * 4 + 0) * 5 + ea];
                o.y = jbuf[(es * 4 + ea) * 5 + 1] - jbuf[(es * 4 + 1) * 5 + ea];
                o.z = jbuf[(es * 4 + ea) * 5 + 2] - jbuf[(es * 4 + 2) * 5 + ea];
                o.w = jbuf[(es * 4 + ea) * 5 + 3] - jbuf[(es * 4 + 3) * 5 + ea];
                *(float4*)(out + sg * 16 + ea * 4) = o;
            }
        }
    }
}

extern "C" void kernel_launch(void* const* d_in, const int* in_sizes, int n_in,
                              void* d_out, int out_size, void* d_ws, size_t ws_size,
                              hipStream_t stream)
{
    const float* u  = (const float*)d_in[0];
    const float* W1 = (const float*)d_in[1];
    const float* b1 = (const float*)d_in[2];
    const float* W2 = (const float*)d_in[3];
    const float* b2 = (const float*)d_in[4];
    const float* W3 = (const float*)d_in[5];
    const float* b3 = (const float*)d_in[6];
    const float* W4 = (const float*)d_in[7];
    // d_in[8] = b4: unused (bias does not enter the Jacobian)
    float* out = (float*)d_out;
    unsigned short* wsb = (unsigned short*)d_ws;   // needs 70656 B

    const int B = in_sizes[0] / 4;
    hipLaunchKernelGGL(conv_w_kernel, dim3((WS_TOT + 255) / 256), dim3(256), 0, stream,
                       W1, W2, W3, W4, wsb);
    const int nblocks = (B + 63) / 64;
    hipLaunchKernelGGL(wnn_jac_kernel, dim3(nblocks), dim3(256), 0, stream,
                       u, W1, b1, W2, b2, W3, b3, wsb, out, B);
}

// Round 14
// 563.888 us; speedup vs baseline: 3.6657x; 1.2514x over previous
//
#include <hip/hip_runtime.h>

#define HIDN 128
#define VSTR 272           // LDS V-buffer row stride BYTES (17x16B -> conflict-free b128)
#define ASTR 132           // f32 activation row stride (floats)

// d_ws byte offsets — ALL weight rows padded to non-power-of-2 byte strides so
// consecutive rows do not alias L2 channels (R14 theory: 512B/256B row strides
// serialize the L2 request stream; 528B = 8.25 lines, 272B = 4.25 lines).
#define WSB_W2F 0                    // f32 [128][132B-padded row=528B]
#define WSB_W3F 67584
#define WSB_W2B 135168               // bf16 [128][row=272B]
#define WSB_W3B 169984
#define WSB_W4B 204800               // bf16 [16][row=272B] (rows 4..15 zero)
#define WSB_W1T 209152               // bf16 [4][128] contiguous (256B rows, tiny)
#define WSB_TOT 210176

typedef __attribute__((ext_vector_type(8))) short short8;
typedef __attribute__((ext_vector_type(4))) float f32x4;

// Batched 8-row W load (f32x4 each), rows 528B apart (de-aliased channels).
#define LOAD_W8(dst, base)                                                    \
    asm volatile("global_load_dwordx4 %0, %8, off\n\t"                        \
                 "global_load_dwordx4 %1, %8, off offset:528\n\t"             \
                 "global_load_dwordx4 %2, %8, off offset:1056\n\t"            \
                 "global_load_dwordx4 %3, %8, off offset:1584\n\t"            \
                 "global_load_dwordx4 %4, %8, off offset:2112\n\t"            \
                 "global_load_dwordx4 %5, %8, off offset:2640\n\t"            \
                 "global_load_dwordx4 %6, %8, off offset:3168\n\t"            \
                 "global_load_dwordx4 %7, %8, off offset:3696\n\t"            \
                 "s_waitcnt vmcnt(0)"                                         \
                 : "=&v"(dst[0]), "=&v"(dst[1]), "=&v"(dst[2]), "=&v"(dst[3]),\
                   "=&v"(dst[4]), "=&v"(dst[5]), "=&v"(dst[6]), "=&v"(dst[7]) \
                 : "v"(base)                                                  \
                 : "memory")

// Batched 4-slice bf16 W load (short8 each), slices 64B apart within a row.
#define LOAD_A4(dst, base)                                                    \
    asm volatile("global_load_dwordx4 %0, %4, off\n\t"                        \
                 "global_load_dwordx4 %1, %4, off offset:64\n\t"              \
                 "global_load_dwordx4 %2, %4, off offset:128\n\t"             \
                 "global_load_dwordx4 %3, %4, off offset:192\n\t"             \
                 "s_waitcnt vmcnt(0)"                                         \
                 : "=&v"(dst[0]), "=&v"(dst[1]), "=&v"(dst[2]), "=&v"(dst[3]) \
                 : "v"(base)                                                  \
                 : "memory")

// f32 -> bf16 round-to-nearest-even
__device__ __forceinline__ unsigned short f2bf(float f) {
    unsigned b = __float_as_uint(f);
    b += 0x7FFFu + ((b >> 16) & 1u);
    return (unsigned short)(b >> 16);
}

// ---------- prelude: one-time weight repack (padded strides) into ws ----------
__global__ void conv_w_kernel(const float* __restrict__ W1, const float* __restrict__ W2,
                              const float* __restrict__ W3, const float* __restrict__ W4,
                              unsigned char* __restrict__ ws)
{
    const int idx = blockIdx.x * 256 + threadIdx.x;
    if (idx < 16384) {
        const int r = idx >> 7, c = idx & 127;
        *(float*)(ws + WSB_W2F + r * 528 + c * 4) = W2[idx];          // f32 verbatim (bit-exact)
        *(float*)(ws + WSB_W3F + r * 528 + c * 4) = W3[idx];
        *(unsigned short*)(ws + WSB_W2B + r * 272 + c * 2) = f2bf(W2[idx]);
        *(unsigned short*)(ws + WSB_W3B + r * 272 + c * 2) = f2bf(W3[idx]);
    } else if (idx < 16384 + 2048) {
        const int t = idx - 16384;
        const int r = t >> 7, c = t & 127;
        *(unsigned short*)(ws + WSB_W4B + r * 272 + c * 2) =
            (r < 4) ? f2bf(W4[r * HIDN + c]) : (unsigned short)0;
    } else if (idx < 16384 + 2048 + 512) {
        const int t = idx - 16384 - 2048;
        const int cc = t >> 7, j = t & 127;
        *(unsigned short*)(ws + WSB_W1T + cc * 256 + j * 2) = f2bf(W1[j * 4 + cc]);
    }
}

// One tangent layer, PING-PONG (src != dst; in-place corrupts — R6/R8, 2-for-2).
// Wave owns V rows [wv*16, wv*16+16). A = W rows (bf16, 272B-padded), B = V cols.
// D[m=unit ib*16+lk*4+r][n=sc=wv*16+lr] -> one b64 store per (ib). R7/R9/R13-proven.
__device__ __forceinline__ void tangent_layer(const unsigned char* __restrict__ src,
                                              unsigned char* __restrict__ dst,
                                              const unsigned char* __restrict__ Wb, // 272B rows
                                              const unsigned char* __restrict__ msk, // [16][16]
                                              int wv, int lr, int lk)
{
    short8 b[4];
    #pragma unroll
    for (int ks = 0; ks < 4; ++ks)
        b[ks] = *(const short8*)(src + (wv * 16 + lr) * VSTR + ks * 64 + lk * 16);

    const int sc = wv * 16 + lr;
    #pragma unroll
    for (int ib = 0; ib < 8; ++ib) {
        short8 a[4];
        LOAD_A4(a, Wb + (ib * 16 + lr) * 272 + lk * 16);
        f32x4 c = (f32x4){0.f, 0.f, 0.f, 0.f};
        #pragma unroll
        for (int ks = 0; ks < 4; ++ks)
            c = __builtin_amdgcn_mfma_f32_16x16x32_bf16(a[ks], b[ks], c, 0, 0, 0);
        const unsigned bits = (msk[(sc >> 2) * 16 + ib * 2 + (lk >> 1)] >> ((lk & 1) * 4)) & 0xFu;
        unsigned long long pk = 0;
        #pragma unroll
        for (int r = 0; r < 4; ++r) {
            const unsigned short v = ((bits >> r) & 1u) ? f2bf(c[r]) : (unsigned short)0;
            pk |= (unsigned long long)v << (r * 16);
        }
        *(unsigned long long*)(dst + sc * VSTR + ib * 32 + lk * 8) = pk;
    }
}

__global__ __launch_bounds__(256, 4)
void wnn_jac_kernel(const float* __restrict__ u,
                    const float* __restrict__ W1, const float* __restrict__ b1,
                    const float* __restrict__ b2, const float* __restrict__ b3,
                    const unsigned char* __restrict__ wsb,
                    float* __restrict__ out, int Btot)
{
    // [0,17408) vA ; [17408,34816) vB ; forward aliases [0,33792) as f32 abuf[64][132]
    __shared__ __align__(16) unsigned char smem[34816];
    __shared__ unsigned char mlds8[3][64][16];   // [layer][sample][unit>>3] (3072 B)
    __shared__ float jbuf[64 * 5];               // [sc][c'] stride 5 (1280 B)

    unsigned char* vA = smem;
    unsigned char* vB = smem + 17408;
    float* abuf = (float*)smem;

    const int tid  = threadIdx.x;
    const int sgp  = tid >> 4;        // sample group: samples sgp*4 .. +4
    const int ugp  = tid & 15;        // unit group: units ugp*8 .. +8
    const int i0   = ugp * 8;
    const long sg0 = (long)blockIdx.x * 64;

    // ======== forward layer 1: 4 samples x 8 units (bit-exact seq chain, bias after) ========
    {
        float4 uvv[4];
        #pragma unroll
        for (int sm = 0; sm < 4; ++sm) {
            const long sg = sg0 + sgp * 4 + sm;
            uvv[sm] = (sg < (long)Btot) ? *(const float4*)(u + sg * 4)
                                        : make_float4(0.f, 0.f, 0.f, 0.f);
        }
        float4 w1r[8];
        #pragma unroll
        for (int ii = 0; ii < 8; ++ii)
            w1r[ii] = *(const float4*)(W1 + (i0 + ii) * 4);
        #pragma unroll
        for (int sm = 0; sm < 4; ++sm) {
            const int s = sgp * 4 + sm;
            unsigned m = 0;
            #pragma unroll
            for (int ii = 0; ii < 8; ++ii) {
                float h = 0.f;
                h = fmaf(w1r[ii].x, uvv[sm].x, h);
                h = fmaf(w1r[ii].y, uvv[sm].y, h);
                h = fmaf(w1r[ii].z, uvv[sm].z, h);
                h = fmaf(w1r[ii].w, uvv[sm].w, h);
                h = h + b1[i0 + ii];
                if (h > 0.f) m |= (1u << ii);
                abuf[s * ASTR + i0 + ii] = fmaxf(h, 0.f);
            }
            mlds8[0][s][ugp] = (unsigned char)m;
        }
    }
    __syncthreads();   // B1: a1 complete

    // ======== forward layer 2: 4x8 register tile, asm-batched W loads (528B rows) ========
    float acc[4][8];
    {
        #pragma unroll
        for (int sm = 0; sm < 4; ++sm)
            #pragma unroll
            for (int ii = 0; ii < 8; ++ii) acc[sm][ii] = 0.f;

        #pragma unroll 1
        for (int jc = 0; jc < 32; ++jc) {
            f32x4 av[4];
            #pragma unroll
            for (int sm = 0; sm < 4; ++sm)
                av[sm] = *(const f32x4*)(abuf + (sgp * 4 + sm) * ASTR + jc * 4);
            f32x4 wreg[8];
            LOAD_W8(wreg, wsb + WSB_W2F + i0 * 528 + jc * 16);
            #pragma unroll
            for (int sm = 0; sm < 4; ++sm) {
                #pragma unroll
                for (int ii = 0; ii < 8; ++ii) {
                    float a = acc[sm][ii];
                    a = fmaf(wreg[ii][0], av[sm][0], a);
                    a = fmaf(wreg[ii][1], av[sm][1], a);
                    a = fmaf(wreg[ii][2], av[sm][2], a);
                    a = fmaf(wreg[ii][3], av[sm][3], a);
                    acc[sm][ii] = a;
                }
            }
        }
    }
    __syncthreads();   // B2: all a1 reads done -> safe to overwrite abuf with a2

    {
        #pragma unroll
        for (int sm = 0; sm < 4; ++sm) {
            const int s = sgp * 4 + sm;
            unsigned m = 0;
            #pragma unroll
            for (int ii = 0; ii < 8; ++ii) {
                const float h = acc[sm][ii] + b2[i0 + ii];
                if (h > 0.f) m |= (1u << ii);
                abuf[s * ASTR + i0 + ii] = fmaxf(h, 0.f);
            }
            mlds8[1][s][ugp] = (unsigned char)m;
        }
    }
    __syncthreads();   // B3: a2 complete

    // ======== forward layer 3 (mask only) ========
    {
        #pragma unroll
        for (int sm = 0; sm < 4; ++sm)
            #pragma unroll
            for (int ii = 0; ii < 8; ++ii) acc[sm][ii] = 0.f;

        #pragma unroll 1
        for (int jc = 0; jc < 32; ++jc) {
            f32x4 av[4];
            #pragma unroll
            for (int sm = 0; sm < 4; ++sm)
                av[sm] = *(const f32x4*)(abuf + (sgp * 4 + sm) * ASTR + jc * 4);
            f32x4 wreg[8];
            LOAD_W8(wreg, wsb + WSB_W3F + i0 * 528 + jc * 16);
            #pragma unroll
            for (int sm = 0; sm < 4; ++sm) {
                #pragma unroll
                for (int ii = 0; ii < 8; ++ii) {
                    float a = acc[sm][ii];
                    a = fmaf(wreg[ii][0], av[sm][0], a);
                    a = fmaf(wreg[ii][1], av[sm][1], a);
                    a = fmaf(wreg[ii][2], av[sm][2], a);
                    a = fmaf(wreg[ii][3], av[sm][3], a);
                    acc[sm][ii] = a;
                }
            }
        }
        #pragma unroll
        for (int sm = 0; sm < 4; ++sm) {
            const int s = sgp * 4 + sm;
            unsigned m = 0;
            #pragma unroll
            for (int ii = 0; ii < 8; ++ii) {
                const float h = acc[sm][ii] + b3[i0 + ii];
                if (h > 0.f) m |= (1u << ii);
            }
            mlds8[2][s][ugp] = (unsigned char)m;
        }
    }

    // ================== TANGENT: 4 subtiles of 16 samples (R13-validated) ==================
    const unsigned char* ml8 = &mlds8[0][0][0];
    const int lane = tid & 63, wv = tid >> 6;
    const int lr = lane & 15, lk = lane >> 4;

    #pragma unroll 1
    for (int st = 0; st < 4; ++st) {
        __syncthreads();   // 1st iter: masks visible + abuf dead; later: jbuf/vA reuse safe

        // ---- v1 build: vA row sc=s_local*4+c = bf16(m1[sample][j] * W1[j][c]) ----
        {
            const int row = tid >> 2, kq = tid & 3;
            const int vs = row >> 2, vc = row & 3;
            const unsigned char* mrec = ml8 + (0 * 64 + st * 16 + vs) * 16;
            const unsigned short* w1t = (const unsigned short*)(wsb + WSB_W1T) + vc * HIDN;
            #pragma unroll
            for (int t = 0; t < 4; ++t) {
                const int j0 = kq * 32 + t * 8;
                const short8 w = *(const short8*)(w1t + j0);
                short8 fr;
                #pragma unroll
                for (int e = 0; e < 8; ++e) {
                    const int j = j0 + e;
                    fr[e] = ((mrec[j >> 3] >> (j & 7)) & 1u) ? w[e] : (short)0;
                }
                *(short8*)(vA + row * VSTR + j0 * 2) = fr;
            }
        }

        // ---- tangent layers 2,3 (ping-pong vA -> vB -> vA; wave-private rows) ----
        tangent_layer(vA, vB, wsb + WSB_W2B, ml8 + (1 * 64 + st * 16) * 16, wv, lr, lk);
        tangent_layer(vB, vA, wsb + WSB_W3B, ml8 + (2 * 64 + st * 16) * 16, wv, lr, lk);

        // ---- Jf: D[c'][sc] = sum_j W4[c'][j] * V3[sc][j] ----
        {
            short8 a4f[4], b[4];
            #pragma unroll
            for (int ks = 0; ks < 4; ++ks) {
                a4f[ks] = *(const short8*)(wsb + WSB_W4B + lr * 272 + ks * 64 + lk * 16);
                b[ks]   = *(const short8*)(vA + (wv * 16 + lr) * VSTR + ks * 64 + lk * 16);
            }
            f32x4 c = (f32x4){0.f, 0.f, 0.f, 0.f};
            #pragma unroll
            for (int ks = 0; ks < 4; ++ks)
                c = __builtin_amdgcn_mfma_f32_16x16x32_bf16(a4f[ks], b[ks], c, 0, 0, 0);
            if (lk == 0) {
                const int sc = wv * 16 + lr;
                #pragma unroll
                for (int r = 0; r < 4; ++r)
                    jbuf[sc * 5 + r] = c[r];
            }
        }
        __syncthreads();   // jbuf complete

        // ---- epilogue: out[s][a][b'] = Jf[b'][a] - Jf[a][b'] ----
        if (tid < 64) {
            const int es = tid >> 2, ea = tid & 3;
            const long sg = sg0 + st * 16 + es;
            if (sg < (long)Btot) {
                float4 o;
                o.x = jbuf[(es * 4 + ea) * 5 + 0] - jbuf[(es * 4 + 0) * 5 + ea];
                o.y = jbuf[(es * 4 + ea) * 5 + 1] - jbuf[(es * 4 + 1) * 5 + ea];
                o.z = jbuf[(es * 4 + ea) * 5 + 2] - jbuf[(es * 4 + 2) * 5 + ea];
                o.w = jbuf[(es * 4 + ea) * 5 + 3] - jbuf[(es * 4 + 3) * 5 + ea];
                *(float4*)(out + sg * 16 + ea * 4) = o;
            }
        }
    }
}

extern "C" void kernel_launch(void* const* d_in, const int* in_sizes, int n_in,
                              void* d_out, int out_size, void* d_ws, size_t ws_size,
                              hipStream_t stream)
{
    const float* u  = (const float*)d_in[0];
    const float* W1 = (const float*)d_in[1];
    const float* b1 = (const float*)d_in[2];
    const float* W2 = (const float*)d_in[3];
    const float* b2 = (const float*)d_in[4];
    const float* W3 = (const float*)d_in[5];
    const float* b3 = (const float*)d_in[6];
    const float* W4 = (const float*)d_in[7];
    // d_in[8] = b4: unused (bias does not enter the Jacobian)
    float* out = (float*)d_out;
    unsigned char* wsb = (unsigned char*)d_ws;   // needs 210176 B

    const int B = in_sizes[0] / 4;
    hipLaunchKernelGGL(conv_w_kernel, dim3((16384 + 2048 + 512 + 255) / 256), dim3(256), 0, stream,
                       W1, W2, W3, W4, wsb);
    const int nblocks = (B + 63) / 64;
    hipLaunchKernelGGL(wnn_jac_kernel, dim3(nblocks), dim3(256), 0, stream,
                       u, W1, b1, b2, b3, wsb, out, B);
}

// Round 15
// 337.700 us; speedup vs baseline: 6.1210x; 1.6698x over previous
//
#include <hip/hip_runtime.h>

#define HIDN 128
#define VSTR 272           // LDS V-buffer row stride BYTES (17x16B -> conflict-free b128)
#define ASTR 132           // f32 activation row stride (floats) — 4s mod 32 banks, conflict-free

// d_ws byte offsets — weight rows padded to non-power-of-2 byte strides (R14 win).
#define WSB_W2F 0                    // f32 [128] rows, stride 528B
#define WSB_W3F 67584
#define WSB_W2B 135168               // bf16 [128] rows, stride 272B
#define WSB_W3B 169984
#define WSB_W4B 204800               // bf16 [16] rows, stride 272B (rows 4..15 zero)
#define WSB_W1T 209152               // bf16 [4][128] contiguous
#define WSB_TOT 210176

typedef __attribute__((ext_vector_type(8))) short short8;
typedef __attribute__((ext_vector_type(4))) float f32x4;

// Batched 4-slice bf16 W load (short8 each), slices 64B apart within a 272B row.
#define LOAD_A4(dst, base)                                                    \
    asm volatile("global_load_dwordx4 %0, %4, off\n\t"                        \
                 "global_load_dwordx4 %1, %4, off offset:64\n\t"              \
                 "global_load_dwordx4 %2, %4, off offset:128\n\t"             \
                 "global_load_dwordx4 %3, %4, off offset:192\n\t"             \
                 "s_waitcnt vmcnt(0)"                                         \
                 : "=&v"(dst[0]), "=&v"(dst[1]), "=&v"(dst[2]), "=&v"(dst[3]) \
                 : "v"(base)                                                  \
                 : "memory")

// f32 -> bf16 round-to-nearest-even
__device__ __forceinline__ unsigned short f2bf(float f) {
    unsigned b = __float_as_uint(f);
    b += 0x7FFFu + ((b >> 16) & 1u);
    return (unsigned short)(b >> 16);
}

// ---------- prelude: one-time weight repack (padded strides) into ws ----------
__global__ void conv_w_kernel(const float* __restrict__ W1, const float* __restrict__ W2,
                              const float* __restrict__ W3, const float* __restrict__ W4,
                              unsigned char* __restrict__ ws)
{
    const int idx = blockIdx.x * 256 + threadIdx.x;
    if (idx < 16384) {
        const int r = idx >> 7, c = idx & 127;
        *(float*)(ws + WSB_W2F + r * 528 + c * 4) = W2[idx];          // f32 verbatim (bit-exact)
        *(float*)(ws + WSB_W3F + r * 528 + c * 4) = W3[idx];
        *(unsigned short*)(ws + WSB_W2B + r * 272 + c * 2) = f2bf(W2[idx]);
        *(unsigned short*)(ws + WSB_W3B + r * 272 + c * 2) = f2bf(W3[idx]);
    } else if (idx < 16384 + 2048) {
        const int t = idx - 16384;
        const int r = t >> 7, c = t & 127;
        *(unsigned short*)(ws + WSB_W4B + r * 272 + c * 2) =
            (r < 4) ? f2bf(W4[r * HIDN + c]) : (unsigned short)0;
    } else if (idx < 16384 + 2048 + 512) {
        const int t = idx - 16384 - 2048;
        const int cc = t >> 7, j = t & 127;
        *(unsigned short*)(ws + WSB_W1T + cc * 256 + j * 2) = f2bf(W1[j * 4 + cc]);
    }
}

// One tangent layer, PING-PONG (src != dst; in-place corrupts — R6/R8, 2-for-2).
// Wave owns V rows [wv*16, wv*16+16). A = W rows (bf16, 272B-padded), B = V cols.
// R7/R9/R13/R14-proven, byte-identical to R14.
__device__ __forceinline__ void tangent_layer(const unsigned char* __restrict__ src,
                                              unsigned char* __restrict__ dst,
                                              const unsigned char* __restrict__ Wb, // 272B rows
                                              const unsigned char* __restrict__ msk, // [16][16]
                                              int wv, int lr, int lk)
{
    short8 b[4];
    #pragma unroll
    for (int ks = 0; ks < 4; ++ks)
        b[ks] = *(const short8*)(src + (wv * 16 + lr) * VSTR + ks * 64 + lk * 16);

    const int sc = wv * 16 + lr;
    #pragma unroll
    for (int ib = 0; ib < 8; ++ib) {
        short8 a[4];
        LOAD_A4(a, Wb + (ib * 16 + lr) * 272 + lk * 16);
        f32x4 c = (f32x4){0.f, 0.f, 0.f, 0.f};
        #pragma unroll
        for (int ks = 0; ks < 4; ++ks)
            c = __builtin_amdgcn_mfma_f32_16x16x32_bf16(a[ks], b[ks], c, 0, 0, 0);
        const unsigned bits = (msk[(sc >> 2) * 16 + ib * 2 + (lk >> 1)] >> ((lk & 1) * 4)) & 0xFu;
        unsigned long long pk = 0;
        #pragma unroll
        for (int r = 0; r < 4; ++r) {
            const unsigned short v = ((bits >> r) & 1u) ? f2bf(c[r]) : (unsigned short)0;
            pk |= (unsigned long long)v << (r * 16);
        }
        *(unsigned long long*)(dst + sc * VSTR + ib * 32 + lk * 8) = pk;
    }
}

__global__ __launch_bounds__(256, 4)
void wnn_jac_kernel(const float* __restrict__ u,
                    const float* __restrict__ W1, const float* __restrict__ b1,
                    const float* __restrict__ b2, const float* __restrict__ b3,
                    const unsigned char* __restrict__ wsb,
                    float* __restrict__ out, int Btot)
{
    // [0,17408) vA ; [17408,34816) vB ; forward aliases [0,33792) as f32 abuf[64][132]
    __shared__ __align__(16) unsigned char smem[34816];
    __shared__ unsigned char mlds8[3][64][16];   // [layer][sample][unit>>3] (3072 B)
    __shared__ float jbuf[64 * 5];               // [sc][c'] stride 5 (1280 B)

    unsigned char* vA = smem;
    unsigned char* vB = smem + 17408;
    float* abuf = (float*)smem;

    const int tid  = threadIdx.x;
    const long sg0 = (long)blockIdx.x * 64;

    // ================== FORWARD: lane = sample, wave = unit-quarter (uniform W) ==================
    {
        const int ls = tid & 63;                                   // sample
        const int wq = __builtin_amdgcn_readfirstlane(tid >> 6);   // uniform quarter 0..3
        const int i0 = wq * 32;
        const bool valid = (sg0 + ls < (long)Btot);

        float4 uv = make_float4(0.f, 0.f, 0.f, 0.f);
        if (valid) uv = *(const float4*)(u + (sg0 + ls) * 4);

        // ---- layer 1: 32 units/wave (uniform W1 rows), bit-exact chain, bias after ----
        {
            unsigned m = 0;
            #pragma unroll
            for (int ii = 0; ii < 32; ++ii) {
                const int i = i0 + ii;
                const float4 w = *(const float4*)(W1 + i * 4);     // uniform
                float h = 0.f;
                h = fmaf(w.x, uv.x, h);
                h = fmaf(w.y, uv.y, h);
                h = fmaf(w.z, uv.z, h);
                h = fmaf(w.w, uv.w, h);
                h = h + b1[i];
                if (h > 0.f) m |= (1u << ii);
                abuf[ls * ASTR + i] = fmaxf(h, 0.f);
            }
            *(unsigned*)&mlds8[0][ls][wq * 4] = m;
        }
        __syncthreads();   // B1: a1 complete

        // ---- layer 2: uniform W rows (scalar path), lane-local activations from LDS ----
        float acc2[32];
        {
            #pragma unroll
            for (int u8 = 0; u8 < 4; ++u8) {
                float acc[8];
                #pragma unroll
                for (int e = 0; e < 8; ++e) acc[e] = 0.f;
                #pragma unroll 4
                for (int jc = 0; jc < 32; ++jc) {
                    const f32x4 av = *(const f32x4*)(abuf + ls * ASTR + jc * 4);
                    #pragma unroll
                    for (int e = 0; e < 8; ++e) {
                        const float* wr = (const float*)(wsb + WSB_W2F
                                              + (i0 + u8 * 8 + e) * 528 + jc * 16); // uniform
                        float a = acc[e];
                        a = fmaf(wr[0], av[0], a);
                        a = fmaf(wr[1], av[1], a);
                        a = fmaf(wr[2], av[2], a);
                        a = fmaf(wr[3], av[3], a);
                        acc[e] = a;
                    }
                }
                #pragma unroll
                for (int e = 0; e < 8; ++e) acc2[u8 * 8 + e] = acc[e];
            }
        }
        __syncthreads();   // B2: ALL a1 reads complete -> safe to overwrite abuf with a2
        {
            unsigned m = 0;
            #pragma unroll
            for (int ii = 0; ii < 32; ++ii) {
                const float h = acc2[ii] + b2[i0 + ii];
                if (h > 0.f) m |= (1u << ii);
                abuf[ls * ASTR + i0 + ii] = fmaxf(h, 0.f);
            }
            *(unsigned*)&mlds8[1][ls][wq * 4] = m;
        }
        __syncthreads();   // B3: a2 complete

        // ---- layer 3 (mask only) ----
        {
            #pragma unroll
            for (int u8 = 0; u8 < 4; ++u8) {
                float acc[8];
                #pragma unroll
                for (int e = 0; e < 8; ++e) acc[e] = 0.f;
                #pragma unroll 4
                for (int jc = 0; jc < 32; ++jc) {
                    const f32x4 av = *(const f32x4*)(abuf + ls * ASTR + jc * 4);
                    #pragma unroll
                    for (int e = 0; e < 8; ++e) {
                        const float* wr = (const float*)(wsb + WSB_W3F
                                              + (i0 + u8 * 8 + e) * 528 + jc * 16); // uniform
                        float a = acc[e];
                        a = fmaf(wr[0], av[0], a);
                        a = fmaf(wr[1], av[1], a);
                        a = fmaf(wr[2], av[2], a);
                        a = fmaf(wr[3], av[3], a);
                        acc[e] = a;
                    }
                }
                #pragma unroll
                for (int e = 0; e < 8; ++e) acc2[u8 * 8 + e] = acc[e];
            }
            unsigned m = 0;
            #pragma unroll
            for (int ii = 0; ii < 32; ++ii) {
                const float h = acc2[ii] + b3[i0 + ii];
                if (h > 0.f) m |= (1u << ii);
            }
            *(unsigned*)&mlds8[2][ls][wq * 4] = m;
        }
    }

    // ================== TANGENT: 4 subtiles of 16 samples (R14-identical) ==================
    const unsigned char* ml8 = &mlds8[0][0][0];
    const int lane = tid & 63, wv = tid >> 6;
    const int lr = lane & 15, lk = lane >> 4;

    #pragma unroll 1
    for (int st = 0; st < 4; ++st) {
        __syncthreads();   // 1st iter: masks visible + abuf dead; later: jbuf/vA reuse safe

        // ---- v1 build: vA row sc=s_local*4+c = bf16(m1[sample][j] * W1[j][c]) ----
        {
            const int row = tid >> 2, kq = tid & 3;
            const int vs = row >> 2, vc = row & 3;
            const unsigned char* mrec = ml8 + (0 * 64 + st * 16 + vs) * 16;
            const unsigned short* w1t = (const unsigned short*)(wsb + WSB_W1T) + vc * HIDN;
            #pragma unroll
            for (int t = 0; t < 4; ++t) {
                const int j0 = kq * 32 + t * 8;
                const short8 w = *(const short8*)(w1t + j0);
                short8 fr;
                #pragma unroll
                for (int e = 0; e < 8; ++e) {
                    const int j = j0 + e;
                    fr[e] = ((mrec[j >> 3] >> (j & 7)) & 1u) ? w[e] : (short)0;
                }
                *(short8*)(vA + row * VSTR + j0 * 2) = fr;
            }
        }

        // ---- tangent layers 2,3 (ping-pong vA -> vB -> vA; wave-private rows) ----
        tangent_layer(vA, vB, wsb + WSB_W2B, ml8 + (1 * 64 + st * 16) * 16, wv, lr, lk);
        tangent_layer(vB, vA, wsb + WSB_W3B, ml8 + (2 * 64 + st * 16) * 16, wv, lr, lk);

        // ---- Jf: D[c'][sc] = sum_j W4[c'][j] * V3[sc][j] ----
        {
            short8 a4f[4], b[4];
            #pragma unroll
            for (int ks = 0; ks < 4; ++ks) {
                a4f[ks] = *(const short8*)(wsb + WSB_W4B + lr * 272 + ks * 64 + lk * 16);
                b[ks]   = *(const short8*)(vA + (wv * 16 + lr) * VSTR + ks * 64 + lk * 16);
            }
            f32x4 c = (f32x4){0.f, 0.f, 0.f, 0.f};
            #pragma unroll
            for (int ks = 0; ks < 4; ++ks)
                c = __builtin_amdgcn_mfma_f32_16x16x32_bf16(a4f[ks], b[ks], c, 0, 0, 0);
            if (lk == 0) {
                const int sc = wv * 16 + lr;
                #pragma unroll
                for (int r = 0; r < 4; ++r)
                    jbuf[sc * 5 + r] = c[r];
            }
        }
        __syncthreads();   // jbuf complete

        // ---- epilogue: out[s][a][b'] = Jf[b'][a] - Jf[a][b'] ----
        if (tid < 64) {
            const int es = tid >> 2, ea = tid & 3;
            const long sg = sg0 + st * 16 + es;
            if (sg < (long)Btot) {
                float4 o;
                o.x = jbuf[(es * 4 + ea) * 5 + 0] - jbuf[(es * 4 + 0) * 5 + ea];
                o.y = jbuf[(es * 4 + ea) * 5 + 1] - jbuf[(es * 4 + 1) * 5 + ea];
                o.z = jbuf[(es * 4 + ea) * 5 + 2] - jbuf[(es * 4 + 2) * 5 + ea];
                o.w = jbuf[(es * 4 + ea) * 5 + 3] - jbuf[(es * 4 + 3) * 5 + ea];
                *(float4*)(out + sg * 16 + ea * 4) = o;
            }
        }
    }
}

extern "C" void kernel_launch(void* const* d_in, const int* in_sizes, int n_in,
                              void* d_out, int out_size, void* d_ws, size_t ws_size,
                              hipStream_t stream)
{
    const float* u  = (const float*)d_in[0];
    const float* W1 = (const float*)d_in[1];
    const float* b1 = (const float*)d_in[2];
    const float* W2 = (const float*)d_in[3];
    const float* b2 = (const float*)d_in[4];
    const float* W3 = (const float*)d_in[5];
    const float* b3 = (const float*)d_in[6];
    const float* W4 = (const float*)d_in[7];
    // d_in[8] = b4: unused (bias does not enter the Jacobian)
    float* out = (float*)d_out;
    unsigned char* wsb = (unsigned char*)d_ws;   // needs 210176 B

    const int B = in_sizes[0] / 4;
    hipLaunchKernelGGL(conv_w_kernel, dim3((16384 + 2048 + 512 + 255) / 256), dim3(256), 0, stream,
                       W1, W2, W3, W4, wsb);
    const int nblocks = (B + 63) / 64;
    hipLaunchKernelGGL(wnn_jac_kernel, dim3(nblocks), dim3(256), 0, stream,
                       u, W1, b1, b2, b3, wsb, out, B);
}